// Round 11
// baseline (146.385 us; speedup 1.0000x reference)
//
#include <hip/hip_runtime.h>
#include <hip/hip_bf16.h>

// FeatureAlign deformable 3x3 conv, G=4, PAD=1.
// R19 = R16 restored verbatim (best: 56.3us fa_main / 138.3 total; R18's
// literal-offset unroll regressed to 58.5) + ONE zero-register lever:
// s_setprio(1) around the MFMA cluster (T5). With 2 independent blocks/CU
// and post-barrier wave skew there is role diversity for the CU scheduler
// to arbitrate (the regime where T5 paid +4-7% elsewhere). R14 had setprio
// but was confounded by spills; this is its clean A/B vs R16.
// Structure: BK=128 (18 lgkm-only barriers, private global loads stay in
// flight across them), dual c4 sets, XCD-aware remap, 12B meta, packed-f16
// interp, 16B gathers, fa_prep unchanged. Measured walls this respects:
// VGPR=64 (spill wall, 3 repros), LDS<=80KB/block, grid=512 (2 blk/CU).

#define Bn   8
#define CIN  256
#define COUT 256
#define Hn   64
#define Wn   64
#define Gn   4
#define Kn   9
#define CPG  64
#define GK   36

typedef float    f32x4 __attribute__((ext_vector_type(4)));
typedef _Float16 f16x2 __attribute__((ext_vector_type(2)));
typedef _Float16 f16x8 __attribute__((ext_vector_type(8)));

// ---------------------------------------------------------------------------
// Fused prep (unchanged from R11/R15/R16).
//  blocks [0, 1024):        x (b,c,y,x) f32 -> xt (b, y*64+x, c) f16 [NHWC]
//  blocks [1024, 1024+32):  w_deform -> fragment-linear f16 wfrag
// ---------------------------------------------------------------------------
#define SWPAD 1156
#define HWT   32
__global__ void fa_prep(const float* __restrict__ x, const float* __restrict__ w,
                        _Float16* __restrict__ xt, _Float16* __restrict__ wfrag) {
    const int bid = blockIdx.x, t = threadIdx.x;
    __shared__ __align__(16) _Float16 spool[16 * SWPAD];   // 36,992 B
    if (bid < 1024) {
        _Float16* sT = spool;                              // 32*256 elems
        const int b = bid >> 7, tile = bid & 127;
        const int hw0 = tile * HWT;
        const int s = t >> 3, hwq = t & 7;
#pragma unroll
        for (int it = 0; it < 8; it++) {
            int c = it * 32 + s;
            float4 v = *(const float4*)(x + (((size_t)(b * CIN + c)) << 12) + hw0 + hwq * 4);
            const float* vf = (const float*)&v;
#pragma unroll
            for (int j = 0; j < 4; j++) {
                int hw = hwq * 4 + j;
                sT[hw * 256 + (c ^ (hwq << 3))] = (_Float16)vf[j];
            }
        }
        __syncthreads();
        const int cg = t & 31, hwr = t >> 5;
#pragma unroll
        for (int it = 0; it < 4; it++) {
            int hw = it * 8 + hwr;
            int q = hw >> 2;
            f16x8 v = *(const f16x8*)&sT[hw * 256 + ((cg ^ q) << 3)];
            *(f16x8*)&xt[(((size_t)b << 12) + hw0 + hw) * 256 + cg * 8] = v;
        }
    } else {
        _Float16* sw = spool;
        const int mt = (bid - 1024) >> 1, gh = (bid - 1024) & 1;
        const int o0 = mt * 16, g0 = gh * 2;
        const int r = t >> 4, tr = t & 15;
        const float* wp = w + (size_t)(o0 + r) * (CIN * Kn) + g0 * (CPG * Kn);
#pragma unroll
        for (int it = 0; it < 18; it++) {
            int off = it * 64 + tr * 4;
            float4 v = *(const float4*)(wp + off);
            _Float16* d = &sw[r * SWPAD + off];
            d[0] = (_Float16)v.x; d[1] = (_Float16)v.y;
            d[2] = (_Float16)v.z; d[3] = (_Float16)v.w;
        }
        __syncthreads();
#pragma unroll
        for (int it = 0; it < 9; it++) {
            int chunk = it * 256 + t;
            int lane = chunk & 63, ks = (chunk >> 6) & 1, gkl = chunk >> 7;
            int gl = gkl / Kn, k = gkl - gl * Kn;
            int gk = g0 * Kn + gkl;
            int ol = lane & 15;
            int cbase = ks * 32 + (lane >> 4) * 8;
            f16x8 v;
#pragma unroll
            for (int j = 0; j < 8; j++)
                v[j] = sw[ol * SWPAD + (gl * CPG + cbase + j) * Kn + k];
            *(f16x8*)&wfrag[(((size_t)gk * 16 + mt) * 2 + ks) * 512 + lane * 8] = v;
        }
    }
}

// ---------------------------------------------------------------------------
// Main: 512 blocks x 512 threads. XCD-aware remap (blk%8 -> XCD):
//   xcd = blk&7, slot = blk>>3; bp = xcd>>1; h = (slot>>1)*2 + (xcd&1);
//   wh = slot&1. Each XCD serves one batch-pair (bijective).
// N = 64 (2 b x 32 w); M = 256 over 8 waves. K = 36*64, BK = 128 (gk pairs).
// ---------------------------------------------------------------------------

// corner gather: loads 4x16B into C4[0..3], weights into AMV
#define ISSUE(C4, AMV, gk) do {                                              \
    int aw_ = s_meta_a[(gk) * 64 + nl];                                      \
    AMV = s_meta_w[(gk) * 64 + nl];                                          \
    unsigned g_ = (unsigned)(gk) / (unsigned)Kn;                             \
    const _Float16* p_ = xt + nBase + g_ * 64u;                              \
    unsigned a00_ = ((unsigned)aw_ & 0xFFFu) << 8;                           \
    unsigned dxo_ = ((unsigned)aw_ & 0x1000u) >> 4;                          \
    unsigned dyo_ = ((unsigned)aw_ & 0x2000u) << 1;                          \
    C4[0] = *(const f16x8*)(p_ + a00_);                                      \
    C4[1] = *(const f16x8*)(p_ + a00_ + dxo_);                               \
    C4[2] = *(const f16x8*)(p_ + a00_ + dyo_);                               \
    C4[3] = *(const f16x8*)(p_ + a00_ + (dxo_ + dyo_));                      \
} while (0)

// packed-f16 bilinear interp of C4 -> sB[BUF][SUB]
#define COMMIT(C4, AMV, BUF, SUB) do {                                       \
    f16x2 wv0_ = __builtin_bit_cast(f16x2, AMV.x);                           \
    f16x2 wv1_ = __builtin_bit_cast(f16x2, AMV.y);                           \
    f16x2 w00_ = __builtin_shufflevector(wv0_, wv0_, 0, 0);                  \
    f16x2 w01_ = __builtin_shufflevector(wv0_, wv0_, 1, 1);                  \
    f16x2 w10_ = __builtin_shufflevector(wv1_, wv1_, 0, 0);                  \
    f16x2 w11_ = __builtin_shufflevector(wv1_, wv1_, 1, 1);                  \
    const f16x2* a0p_ = (const f16x2*)&C4[0];                                \
    const f16x2* a1p_ = (const f16x2*)&C4[1];                                \
    const f16x2* a2p_ = (const f16x2*)&C4[2];                                \
    const f16x2* a3p_ = (const f16x2*)&C4[3];                                \
    f16x8 r_;                                                                \
    f16x2* rp_ = (f16x2*)&r_;                                                \
    _Pragma("unroll")                                                        \
    for (int p = 0; p < 4; p++)                                              \
        rp_[p] = w00_ * a0p_[p] + w01_ * a1p_[p]                             \
               + w10_ * a2p_[p] + w11_ * a3p_[p];                            \
    *(f16x8*)&sB[BUF][SUB][(nl * 8 + (cg ^ (nl & 7))) * 8] = r_;             \
} while (0)

// one gk worth of af/bfv loads + MFMA; COMMIT/ISSUE spliced between loads
// and MFMA so gather latency hides under the matrix work. MFMA cluster is
// wrapped in setprio(1)/(0) (T5).
#define HALF(GKI, RB, SUB, PIPE) do {                                        \
    const _Float16* wbase_ = wfrag + (((size_t)(GKI) * 16 + wid * 2) * 2) * 512; \
    f16x8 af_[2][2];                                                         \
    _Pragma("unroll")                                                        \
    for (int ks = 0; ks < 2; ks++)                                           \
        _Pragma("unroll")                                                    \
        for (int mt = 0; mt < 2; mt++)                                       \
            af_[ks][mt] = *(const f16x8*)(wbase_ + ((size_t)(mt * 2 + ks) * 64 + lane) * 8); \
    f16x8 bfv_[2][4];                                                        \
    _Pragma("unroll")                                                        \
    for (int ks = 0; ks < 2; ks++)                                           \
        _Pragma("unroll")                                                    \
        for (int nt = 0; nt < 4; nt++) {                                     \
            int n = nt * 16 + col;                                           \
            int cq8 = ks * 4 + quad;                                         \
            bfv_[ks][nt] = *(const f16x8*)&sB[RB][SUB][(n * 8 + (cq8 ^ (n & 7))) * 8]; \
        }                                                                    \
    PIPE                                                                     \
    __builtin_amdgcn_s_setprio(1);                                           \
    _Pragma("unroll")                                                        \
    for (int ks = 0; ks < 2; ks++)                                           \
        _Pragma("unroll")                                                    \
        for (int mt = 0; mt < 2; mt++)                                       \
            _Pragma("unroll")                                                 \
            for (int nt = 0; nt < 4; nt++)                                   \
                acc[mt][nt] = __builtin_amdgcn_mfma_f32_16x16x32_f16(        \
                    af_[ks][mt], bfv_[ks][nt], acc[mt][nt], 0, 0, 0);        \
    __builtin_amdgcn_s_setprio(0);                                           \
} while (0)

__global__ __launch_bounds__(512, 4)
void fa_main(const _Float16* __restrict__ xt, const float* __restrict__ shp,
             const float* __restrict__ w_off, const _Float16* __restrict__ wfrag,
             float* __restrict__ out) {
    const int blk = blockIdx.x;
    const int xcd = blk & 7, slot = blk >> 3;
    const int bp = xcd >> 1;
    const int h = (slot >> 1) * 2 + (xcd & 1);
    const int wh = slot & 1;
    const int w0 = wh * 32;
    const int t = threadIdx.x;
    const int wid = t >> 6, lane = t & 63;
    const int col = lane & 15, quad = lane >> 4;
    const int cg = t & 7, nl = (t >> 3) & 63;

    __shared__ int  s_meta_a[GK * 64];                    // 9216 B
    __shared__ __align__(8) int2 s_meta_w[GK * 64];       // 18432 B
    __shared__ __align__(16) _Float16 sB[2][2][64 * 64];  // 32768 B
    __shared__ float s_shp[2 * 4 * 32];                   // 1024 B
    __shared__ float s_woff[GK * 8];                      // 1152 B
    // total 62,592 B -> 2 blocks/CU

    // ---- stage shp slice (2 b x 4 c x 32 w at row h) + ALL 288 w_off ----
    if (t < 256) {
        int bb = t >> 7, c = (t >> 5) & 3, wl = t & 31;
        s_shp[t] = shp[(((bp * 2 + bb) * 4 + c) << 12) + h * Wn + w0 + wl];
    }
    for (int u = t; u < GK * 8; u += 512) s_woff[u] = w_off[u];
    __syncthreads();

    // ---- meta: 12B (int addr+flags, int2 f16x2 weights) per (gk, n) ----
    for (int i = t; i < GK * 64; i += 512) {
        int gk = i >> 6, n = i & 63;
        int bb = n >> 5, wl = n & 31;
        int g = gk / Kn, k = gk - g * Kn;
        int ky = k / 3, kx = k - ky * 3;
        float dy = 0.f, dx = 0.f;
#pragma unroll
        for (int c = 0; c < 4; c++) {
            float sv = s_shp[(bb * 4 + c) * 32 + wl];
            dy = fmaf(s_woff[gk * 8 + c],     sv, dy);
            dx = fmaf(s_woff[gk * 8 + 4 + c], sv, dx);
        }
        float py = (float)(h + ky - 1) + dy;
        float px = (float)(w0 + wl + kx - 1) + dx;
        float y0 = floorf(py), x0 = floorf(px);
        float fy = py - y0, fx = px - x0;
        int iy = (int)y0, ix = (int)x0;
        bool y0v = (unsigned)iy       < (unsigned)Hn;
        bool y1v = (unsigned)(iy + 1) < (unsigned)Hn;
        bool x0v = (unsigned)ix       < (unsigned)Wn;
        bool x1v = (unsigned)(ix + 1) < (unsigned)Wn;
        int yc0 = min(max(iy, 0), Hn - 1), yc1 = min(max(iy + 1, 0), Hn - 1);
        int xc0 = min(max(ix, 0), Wn - 1), xc1 = min(max(ix + 1, 0), Wn - 1);
        int l00 = yc0 * Wn + xc0;
        int dx1 = xc1 - xc0, dy1 = yc1 - yc0;             // in {0,1}
        float wy1 = fy, wy0 = 1.f - fy, wx1 = fx, wx0 = 1.f - fx;
        float w00 = (y0v && x0v) ? wy0 * wx0 : 0.f;
        float w01 = (y0v && x1v) ? wy0 * wx1 : 0.f;
        float w10 = (y1v && x0v) ? wy1 * wx0 : 0.f;
        float w11 = (y1v && x1v) ? wy1 * wx1 : 0.f;
        f16x2 p0, p1;
        p0.x = (_Float16)w00; p0.y = (_Float16)w01;
        p1.x = (_Float16)w10; p1.y = (_Float16)w11;
        s_meta_a[i] = l00 | (dx1 << 12) | (dy1 << 13);
        s_meta_w[i] = make_int2(__builtin_bit_cast(int, p0),
                                __builtin_bit_cast(int, p1));
    }

    f16x8 c4a[4], c4b[4];
    int2  amva, amvb;
    const unsigned nBase = ((unsigned)(bp * 2 + (nl >> 5)) << 20) + (unsigned)cg * 8u;

    f32x4 acc[2][4];
#pragma unroll
    for (int mt = 0; mt < 2; mt++)
#pragma unroll
        for (int nt = 0; nt < 4; nt++) acc[mt][nt] = (f32x4){0.f, 0.f, 0.f, 0.f};

    __syncthreads();            // meta visible

    // prologue: sB[0] = {gk0, gk1}; c4a<-gk2, c4b<-gk3 in flight
    ISSUE(c4a, amva, 0);
    ISSUE(c4b, amvb, 1);
    COMMIT(c4a, amva, 0, 0);
    ISSUE(c4a, amva, 2);
    COMMIT(c4b, amvb, 0, 1);
    ISSUE(c4b, amvb, 3);
    __syncthreads();

    // 18 pair-iterations; ONE lgkm-only barrier each.
    for (int P = 0; P < GK / 2; P++) {
        const int rb = P & 1, wb = rb ^ 1;
        const int g0 = 2 * P;
        HALF(g0, rb, 0,
             if (g0 + 2 < GK) COMMIT(c4a, amva, wb, 0);
             if (g0 + 4 < GK) ISSUE(c4a, amva, g0 + 4); );
        HALF(g0 + 1, rb, 1,
             if (g0 + 3 < GK) COMMIT(c4b, amvb, wb, 1);
             if (g0 + 5 < GK) ISSUE(c4b, amvb, g0 + 5); );
        // lgkm-only barrier: commit ds_writes + bfv/meta ds_reads drained;
        // private global gathers (c4/af) stay in flight across it.
        asm volatile("s_waitcnt lgkmcnt(0)" ::: "memory");
        __builtin_amdgcn_s_barrier();
    }

    // ---- epilogue: o = wid*32 + mt*16 + quad*4 + r ; n = nt*16 + col ----
#pragma unroll
    for (int mt = 0; mt < 2; mt++)
#pragma unroll
        for (int r = 0; r < 4; r++) {
            int o = wid * 32 + mt * 16 + quad * 4 + r;
#pragma unroll
            for (int nt = 0; nt < 4; nt++) {
                int n = nt * 16 + col;
                int b = bp * 2 + (n >> 5);
                int w = w0 + (n & 31);
                out[(((size_t)(b * COUT + o)) << 12) + h * Wn + w] =
                    fmaxf(acc[mt][nt][r], 0.f);
            }
        }
}

// ---------------------------------------------------------------------------
extern "C" void kernel_launch(void* const* d_in, const int* in_sizes, int n_in,
                              void* d_out, int out_size, void* d_ws, size_t ws_size,
                              hipStream_t stream) {
    const float* x     = (const float*)d_in[0];
    const float* shp   = (const float*)d_in[1];
    const float* w_off = (const float*)d_in[2];
    const float* w_def = (const float*)d_in[3];
    float* out = (float*)d_out;
    _Float16* wfrag = (_Float16*)d_ws;                       // 1.18 MB
    _Float16* xt    = (_Float16*)((char*)d_ws + (2u << 20)); // 16.8 MB

    fa_prep<<<1024 + 32, 256, 0, stream>>>(x, w_def, xt, wfrag);
    fa_main<<<512, 512, 0, stream>>>(xt, shp, w_off, wfrag, out);
}

// Round 12
// 137.964 us; speedup vs baseline: 1.0610x; 1.0610x over previous
//
#include <hip/hip_runtime.h>
#include <hip/hip_bf16.h>

// FeatureAlign deformable 3x3 conv, G=4, PAD=1.
// R20 = R16 restored VERBATIM — the session's best verified state
// (fa_main 56.3us, total 138.27us, VGPR 64, WRITE exact 32.8MB, FETCH
// compulsory ~23.8MB, 0 bank conflicts). R19's setprio graft regressed
// (-12us: scheduler-region perturbation -> partial spills; T5 is null in
// barrier-lockstep loops). Walls measured this session, all with repros:
//   - VGPR wall = 64: any added persistent state spills (R13/R14/R17/R19).
//   - Grid wall = 512 blocks = 2 blocks/CU; splitting duplicates the
//     dominant L2 stream (R12: -60%).
//   - Traffic compulsory; L2 gather+af stream ~61% of per-CU share is the
//     largest utilization term; MFMA/VALU/LDS all ~26-35% (latency-bound
//     lockstep with no legal deepening move).
// Structure: BK=128 (18 lgkm-only barriers; private global loads stay in
// flight across them), dual c4 register sets, XCD-aware block remap,
// 12B meta records, packed-f16 interp (v_pk_fma_f16), 16B gathers,
// MFMA 16x16x32_f16, LDS-staged prep transpose.

#define Bn   8
#define CIN  256
#define COUT 256
#define Hn   64
#define Wn   64
#define Gn   4
#define Kn   9
#define CPG  64
#define GK   36

typedef float    f32x4 __attribute__((ext_vector_type(4)));
typedef _Float16 f16x2 __attribute__((ext_vector_type(2)));
typedef _Float16 f16x8 __attribute__((ext_vector_type(8)));

// ---------------------------------------------------------------------------
// Fused prep (unchanged from R11/R15/R16).
//  blocks [0, 1024):        x (b,c,y,x) f32 -> xt (b, y*64+x, c) f16 [NHWC]
//  blocks [1024, 1024+32):  w_deform -> fragment-linear f16 wfrag
// ---------------------------------------------------------------------------
#define SWPAD 1156
#define HWT   32
__global__ void fa_prep(const float* __restrict__ x, const float* __restrict__ w,
                        _Float16* __restrict__ xt, _Float16* __restrict__ wfrag) {
    const int bid = blockIdx.x, t = threadIdx.x;
    __shared__ __align__(16) _Float16 spool[16 * SWPAD];   // 36,992 B
    if (bid < 1024) {
        _Float16* sT = spool;                              // 32*256 elems
        const int b = bid >> 7, tile = bid & 127;
        const int hw0 = tile * HWT;
        const int s = t >> 3, hwq = t & 7;
#pragma unroll
        for (int it = 0; it < 8; it++) {
            int c = it * 32 + s;
            float4 v = *(const float4*)(x + (((size_t)(b * CIN + c)) << 12) + hw0 + hwq * 4);
            const float* vf = (const float*)&v;
#pragma unroll
            for (int j = 0; j < 4; j++) {
                int hw = hwq * 4 + j;
                sT[hw * 256 + (c ^ (hwq << 3))] = (_Float16)vf[j];
            }
        }
        __syncthreads();
        const int cg = t & 31, hwr = t >> 5;
#pragma unroll
        for (int it = 0; it < 4; it++) {
            int hw = it * 8 + hwr;
            int q = hw >> 2;
            f16x8 v = *(const f16x8*)&sT[hw * 256 + ((cg ^ q) << 3)];
            *(f16x8*)&xt[(((size_t)b << 12) + hw0 + hw) * 256 + cg * 8] = v;
        }
    } else {
        _Float16* sw = spool;
        const int mt = (bid - 1024) >> 1, gh = (bid - 1024) & 1;
        const int o0 = mt * 16, g0 = gh * 2;
        const int r = t >> 4, tr = t & 15;
        const float* wp = w + (size_t)(o0 + r) * (CIN * Kn) + g0 * (CPG * Kn);
#pragma unroll
        for (int it = 0; it < 18; it++) {
            int off = it * 64 + tr * 4;
            float4 v = *(const float4*)(wp + off);
            _Float16* d = &sw[r * SWPAD + off];
            d[0] = (_Float16)v.x; d[1] = (_Float16)v.y;
            d[2] = (_Float16)v.z; d[3] = (_Float16)v.w;
        }
        __syncthreads();
#pragma unroll
        for (int it = 0; it < 9; it++) {
            int chunk = it * 256 + t;
            int lane = chunk & 63, ks = (chunk >> 6) & 1, gkl = chunk >> 7;
            int gl = gkl / Kn, k = gkl - gl * Kn;
            int gk = g0 * Kn + gkl;
            int ol = lane & 15;
            int cbase = ks * 32 + (lane >> 4) * 8;
            f16x8 v;
#pragma unroll
            for (int j = 0; j < 8; j++)
                v[j] = sw[ol * SWPAD + (gl * CPG + cbase + j) * Kn + k];
            *(f16x8*)&wfrag[(((size_t)gk * 16 + mt) * 2 + ks) * 512 + lane * 8] = v;
        }
    }
}

// ---------------------------------------------------------------------------
// Main: 512 blocks x 512 threads. XCD-aware remap (blk%8 -> XCD):
//   xcd = blk&7, slot = blk>>3; bp = xcd>>1; h = (slot>>1)*2 + (xcd&1);
//   wh = slot&1. Each XCD serves one batch-pair (bijective).
// N = 64 (2 b x 32 w); M = 256 over 8 waves. K = 36*64, BK = 128 (gk pairs).
// ---------------------------------------------------------------------------

// corner gather: loads 4x16B into C4[0..3], weights into AMV
#define ISSUE(C4, AMV, gk) do {                                              \
    int aw_ = s_meta_a[(gk) * 64 + nl];                                      \
    AMV = s_meta_w[(gk) * 64 + nl];                                          \
    unsigned g_ = (unsigned)(gk) / (unsigned)Kn;                             \
    const _Float16* p_ = xt + nBase + g_ * 64u;                              \
    unsigned a00_ = ((unsigned)aw_ & 0xFFFu) << 8;                           \
    unsigned dxo_ = ((unsigned)aw_ & 0x1000u) >> 4;                          \
    unsigned dyo_ = ((unsigned)aw_ & 0x2000u) << 1;                          \
    C4[0] = *(const f16x8*)(p_ + a00_);                                      \
    C4[1] = *(const f16x8*)(p_ + a00_ + dxo_);                               \
    C4[2] = *(const f16x8*)(p_ + a00_ + dyo_);                               \
    C4[3] = *(const f16x8*)(p_ + a00_ + (dxo_ + dyo_));                      \
} while (0)

// packed-f16 bilinear interp of C4 -> sB[BUF][SUB]
#define COMMIT(C4, AMV, BUF, SUB) do {                                       \
    f16x2 wv0_ = __builtin_bit_cast(f16x2, AMV.x);                           \
    f16x2 wv1_ = __builtin_bit_cast(f16x2, AMV.y);                           \
    f16x2 w00_ = __builtin_shufflevector(wv0_, wv0_, 0, 0);                  \
    f16x2 w01_ = __builtin_shufflevector(wv0_, wv0_, 1, 1);                  \
    f16x2 w10_ = __builtin_shufflevector(wv1_, wv1_, 0, 0);                  \
    f16x2 w11_ = __builtin_shufflevector(wv1_, wv1_, 1, 1);                  \
    const f16x2* a0p_ = (const f16x2*)&C4[0];                                \
    const f16x2* a1p_ = (const f16x2*)&C4[1];                                \
    const f16x2* a2p_ = (const f16x2*)&C4[2];                                \
    const f16x2* a3p_ = (const f16x2*)&C4[3];                                \
    f16x8 r_;                                                                \
    f16x2* rp_ = (f16x2*)&r_;                                                \
    _Pragma("unroll")                                                        \
    for (int p = 0; p < 4; p++)                                              \
        rp_[p] = w00_ * a0p_[p] + w01_ * a1p_[p]                             \
               + w10_ * a2p_[p] + w11_ * a3p_[p];                            \
    *(f16x8*)&sB[BUF][SUB][(nl * 8 + (cg ^ (nl & 7))) * 8] = r_;             \
} while (0)

// one gk worth of af/bfv loads + MFMA; COMMIT/ISSUE spliced between loads
// and MFMA so gather latency hides under the matrix work.
#define HALF(GKI, RB, SUB, PIPE) do {                                        \
    const _Float16* wbase_ = wfrag + (((size_t)(GKI) * 16 + wid * 2) * 2) * 512; \
    f16x8 af_[2][2];                                                         \
    _Pragma("unroll")                                                        \
    for (int ks = 0; ks < 2; ks++)                                           \
        _Pragma("unroll")                                                    \
        for (int mt = 0; mt < 2; mt++)                                       \
            af_[ks][mt] = *(const f16x8*)(wbase_ + ((size_t)(mt * 2 + ks) * 64 + lane) * 8); \
    f16x8 bfv_[2][4];                                                        \
    _Pragma("unroll")                                                        \
    for (int ks = 0; ks < 2; ks++)                                           \
        _Pragma("unroll")                                                    \
        for (int nt = 0; nt < 4; nt++) {                                     \
            int n = nt * 16 + col;                                           \
            int cq8 = ks * 4 + quad;                                         \
            bfv_[ks][nt] = *(const f16x8*)&sB[RB][SUB][(n * 8 + (cq8 ^ (n & 7))) * 8]; \
        }                                                                    \
    PIPE                                                                     \
    _Pragma("unroll")                                                        \
    for (int ks = 0; ks < 2; ks++)                                           \
        _Pragma("unroll")                                                    \
        for (int mt = 0; mt < 2; mt++)                                       \
            _Pragma("unroll")                                                 \
            for (int nt = 0; nt < 4; nt++)                                   \
                acc[mt][nt] = __builtin_amdgcn_mfma_f32_16x16x32_f16(        \
                    af_[ks][mt], bfv_[ks][nt], acc[mt][nt], 0, 0, 0);        \
} while (0)

__global__ __launch_bounds__(512, 4)
void fa_main(const _Float16* __restrict__ xt, const float* __restrict__ shp,
             const float* __restrict__ w_off, const _Float16* __restrict__ wfrag,
             float* __restrict__ out) {
    const int blk = blockIdx.x;
    const int xcd = blk & 7, slot = blk >> 3;
    const int bp = xcd >> 1;
    const int h = (slot >> 1) * 2 + (xcd & 1);
    const int wh = slot & 1;
    const int w0 = wh * 32;
    const int t = threadIdx.x;
    const int wid = t >> 6, lane = t & 63;
    const int col = lane & 15, quad = lane >> 4;
    const int cg = t & 7, nl = (t >> 3) & 63;

    __shared__ int  s_meta_a[GK * 64];                    // 9216 B
    __shared__ __align__(8) int2 s_meta_w[GK * 64];       // 18432 B
    __shared__ __align__(16) _Float16 sB[2][2][64 * 64];  // 32768 B
    __shared__ float s_shp[2 * 4 * 32];                   // 1024 B
    __shared__ float s_woff[GK * 8];                      // 1152 B
    // total 62,592 B -> 2 blocks/CU

    // ---- stage shp slice (2 b x 4 c x 32 w at row h) + ALL 288 w_off ----
    if (t < 256) {
        int bb = t >> 7, c = (t >> 5) & 3, wl = t & 31;
        s_shp[t] = shp[(((bp * 2 + bb) * 4 + c) << 12) + h * Wn + w0 + wl];
    }
    for (int u = t; u < GK * 8; u += 512) s_woff[u] = w_off[u];
    __syncthreads();

    // ---- meta: 12B (int addr+flags, int2 f16x2 weights) per (gk, n) ----
    for (int i = t; i < GK * 64; i += 512) {
        int gk = i >> 6, n = i & 63;
        int bb = n >> 5, wl = n & 31;
        int g = gk / Kn, k = gk - g * Kn;
        int ky = k / 3, kx = k - ky * 3;
        float dy = 0.f, dx = 0.f;
#pragma unroll
        for (int c = 0; c < 4; c++) {
            float sv = s_shp[(bb * 4 + c) * 32 + wl];
            dy = fmaf(s_woff[gk * 8 + c],     sv, dy);
            dx = fmaf(s_woff[gk * 8 + 4 + c], sv, dx);
        }
        float py = (float)(h + ky - 1) + dy;
        float px = (float)(w0 + wl + kx - 1) + dx;
        float y0 = floorf(py), x0 = floorf(px);
        float fy = py - y0, fx = px - x0;
        int iy = (int)y0, ix = (int)x0;
        bool y0v = (unsigned)iy       < (unsigned)Hn;
        bool y1v = (unsigned)(iy + 1) < (unsigned)Hn;
        bool x0v = (unsigned)ix       < (unsigned)Wn;
        bool x1v = (unsigned)(ix + 1) < (unsigned)Wn;
        int yc0 = min(max(iy, 0), Hn - 1), yc1 = min(max(iy + 1, 0), Hn - 1);
        int xc0 = min(max(ix, 0), Wn - 1), xc1 = min(max(ix + 1, 0), Wn - 1);
        int l00 = yc0 * Wn + xc0;
        int dx1 = xc1 - xc0, dy1 = yc1 - yc0;             // in {0,1}
        float wy1 = fy, wy0 = 1.f - fy, wx1 = fx, wx0 = 1.f - fx;
        float w00 = (y0v && x0v) ? wy0 * wx0 : 0.f;
        float w01 = (y0v && x1v) ? wy0 * wx1 : 0.f;
        float w10 = (y1v && x0v) ? wy1 * wx0 : 0.f;
        float w11 = (y1v && x1v) ? wy1 * wx1 : 0.f;
        f16x2 p0, p1;
        p0.x = (_Float16)w00; p0.y = (_Float16)w01;
        p1.x = (_Float16)w10; p1.y = (_Float16)w11;
        s_meta_a[i] = l00 | (dx1 << 12) | (dy1 << 13);
        s_meta_w[i] = make_int2(__builtin_bit_cast(int, p0),
                                __builtin_bit_cast(int, p1));
    }

    f16x8 c4a[4], c4b[4];
    int2  amva, amvb;
    const unsigned nBase = ((unsigned)(bp * 2 + (nl >> 5)) << 20) + (unsigned)cg * 8u;

    f32x4 acc[2][4];
#pragma unroll
    for (int mt = 0; mt < 2; mt++)
#pragma unroll
        for (int nt = 0; nt < 4; nt++) acc[mt][nt] = (f32x4){0.f, 0.f, 0.f, 0.f};

    __syncthreads();            // meta visible

    // prologue: sB[0] = {gk0, gk1}; c4a<-gk2, c4b<-gk3 in flight
    ISSUE(c4a, amva, 0);
    ISSUE(c4b, amvb, 1);
    COMMIT(c4a, amva, 0, 0);
    ISSUE(c4a, amva, 2);
    COMMIT(c4b, amvb, 0, 1);
    ISSUE(c4b, amvb, 3);
    __syncthreads();

    // 18 pair-iterations; ONE lgkm-only barrier each.
    for (int P = 0; P < GK / 2; P++) {
        const int rb = P & 1, wb = rb ^ 1;
        const int g0 = 2 * P;
        HALF(g0, rb, 0,
             if (g0 + 2 < GK) COMMIT(c4a, amva, wb, 0);
             if (g0 + 4 < GK) ISSUE(c4a, amva, g0 + 4); );
        HALF(g0 + 1, rb, 1,
             if (g0 + 3 < GK) COMMIT(c4b, amvb, wb, 1);
             if (g0 + 5 < GK) ISSUE(c4b, amvb, g0 + 5); );
        // lgkm-only barrier: commit ds_writes + bfv/meta ds_reads drained;
        // private global gathers (c4/af) stay in flight across it.
        asm volatile("s_waitcnt lgkmcnt(0)" ::: "memory");
        __builtin_amdgcn_s_barrier();
    }

    // ---- epilogue: o = wid*32 + mt*16 + quad*4 + r ; n = nt*16 + col ----
#pragma unroll
    for (int mt = 0; mt < 2; mt++)
#pragma unroll
        for (int r = 0; r < 4; r++) {
            int o = wid * 32 + mt * 16 + quad * 4 + r;
#pragma unroll
            for (int nt = 0; nt < 4; nt++) {
                int n = nt * 16 + col;
                int b = bp * 2 + (n >> 5);
                int w = w0 + (n & 31);
                out[(((size_t)(b * COUT + o)) << 12) + h * Wn + w] =
                    fmaxf(acc[mt][nt][r], 0.f);
            }
        }
}

// ---------------------------------------------------------------------------
extern "C" void kernel_launch(void* const* d_in, const int* in_sizes, int n_in,
                              void* d_out, int out_size, void* d_ws, size_t ws_size,
                              hipStream_t stream) {
    const float* x     = (const float*)d_in[0];
    const float* shp   = (const float*)d_in[1];
    const float* w_off = (const float*)d_in[2];
    const float* w_def = (const float*)d_in[3];
    float* out = (float*)d_out;
    _Float16* wfrag = (_Float16*)d_ws;                       // 1.18 MB
    _Float16* xt    = (_Float16*)((char*)d_ws + (2u << 20)); // 16.8 MB

    fa_prep<<<1024 + 32, 256, 0, stream>>>(x, w_def, xt, wfrag);
    fa_main<<<512, 512, 0, stream>>>(xt, shp, w_off, wfrag, out);
}